// Round 9
// baseline (82.708 us; speedup 1.0000x reference)
//
#include <hip/hip_runtime.h>
#include <math.h>

// B=4, T=2048, C=768, H=64
#define TB 2048
#define CB 768
#define NB 4
#define NROWS (NB * TB) // 8192
#define SKV 6           // proj K-split
#define NSP 8           // attn KV-split

typedef __attribute__((ext_vector_type(8))) short bf16x8;
typedef __attribute__((ext_vector_type(4))) float f32x4;
typedef __attribute__((ext_vector_type(2))) float f32x2;
typedef __attribute__((ext_vector_type(2))) unsigned int u32x2;
typedef __attribute__((ext_vector_type(4))) unsigned int u32x4;

__device__ inline unsigned short f2bf(float f) {
  union { float f; unsigned u; } v; v.f = f;
  unsigned r = v.u + 0x7FFFu + ((v.u >> 16) & 1u);
  return (unsigned short)(r >> 16);
}
__device__ inline unsigned pack2bf(float a, float b) {
  return (unsigned)f2bf(a) | ((unsigned)f2bf(b) << 16);
}
__device__ inline float bf2f(unsigned short u) {
  union { unsigned u; float f; } v; v.u = (unsigned)u << 16; return v.f;
}

// ---------------- kernel 0: weights fp32 [C][64] x3 -> Wt bf16 [192][768] ----
__global__ void cvt_w_kernel(const float* __restrict__ Wq, const float* __restrict__ Wk,
                             const float* __restrict__ Wv, unsigned short* __restrict__ Wt) {
  __shared__ float tw[64][65];
  const float* W = (blockIdx.y == 0) ? Wq : (blockIdx.y == 1) ? Wk : Wv;
  const int c0 = blockIdx.x * 64;
  const int row = threadIdx.x >> 2, seg = threadIdx.x & 3;
#pragma unroll
  for (int i = 0; i < 4; ++i) {
    float4 f = *(const float4*)(W + (size_t)(c0 + row) * 64 + seg * 16 + i * 4);
    tw[row][seg * 16 + i * 4 + 0] = f.x;
    tw[row][seg * 16 + i * 4 + 1] = f.y;
    tw[row][seg * 16 + i * 4 + 2] = f.z;
    tw[row][seg * 16 + i * 4 + 3] = f.w;
  }
  __syncthreads();
  const int j = threadIdx.x >> 2, cq = threadIdx.x & 3;
  unsigned short* dst = Wt + (size_t)(blockIdx.y * 64 + j) * CB + c0 + cq * 16;
  u32x4 ua, ub;
#pragma unroll
  for (int i = 0; i < 4; ++i) ua[i] = pack2bf(tw[cq * 16 + 2 * i][j], tw[cq * 16 + 2 * i + 1][j]);
#pragma unroll
  for (int i = 0; i < 4; ++i) ub[i] = pack2bf(tw[cq * 16 + 8 + 2 * i][j], tw[cq * 16 + 9 + 2 * i][j]);
  *(u32x4*)dst = ua;
  *(u32x4*)(dst + 8) = ub;
}

// ---------------- kernel 1: QKV projection GEMM, K-split ---------------------
__launch_bounds__(256)
__global__ void proj_kernel(const float* __restrict__ x, const unsigned short* __restrict__ Wt,
                            unsigned short* __restrict__ part, int ksteps) {
  __shared__ __align__(16) unsigned short xs[64 * 64];
  const int tid = threadIdx.x;
  const int wv = tid >> 6;
  const int l = tid & 63;
  const int lrow = l & 15, lg = l >> 4;
  const int m0 = blockIdx.x * 64;
  const int ks = blockIdx.y;
  const int kbase = ks * ksteps * 64;
  const int srow = tid >> 2;
  const int sq = tid & 3;
  const float* xp = x + (size_t)(m0 + srow) * CB + sq * 16;

  f32x4 acc[4][3];
#pragma unroll
  for (int a = 0; a < 4; ++a)
#pragma unroll
    for (int n = 0; n < 3; ++n) acc[a][n] = (f32x4){0.f, 0.f, 0.f, 0.f};

  for (int kk = 0; kk < ksteps; ++kk) {
    int k0 = kbase + kk * 64;
    bf16x8 c0, c1;
#pragma unroll
    for (int i = 0; i < 2; ++i) {
      float4 f = *(const float4*)(xp + k0 + 4 * i);
      c0[4 * i + 0] = (short)f2bf(f.x); c0[4 * i + 1] = (short)f2bf(f.y);
      c0[4 * i + 2] = (short)f2bf(f.z); c0[4 * i + 3] = (short)f2bf(f.w);
    }
#pragma unroll
    for (int i = 0; i < 2; ++i) {
      float4 f = *(const float4*)(xp + k0 + 8 + 4 * i);
      c1[4 * i + 0] = (short)f2bf(f.x); c1[4 * i + 1] = (short)f2bf(f.y);
      c1[4 * i + 2] = (short)f2bf(f.z); c1[4 * i + 3] = (short)f2bf(f.w);
    }
    {
      char* base = (char*)xs + srow * 128;
      int swz = (srow & 7) << 4;
      *(bf16x8*)(base + ((sq * 32 + 0) ^ swz)) = c0;
      *(bf16x8*)(base + ((sq * 32 + 16) ^ swz)) = c1;
    }
    __syncthreads();

#pragma unroll
    for (int s = 0; s < 2; ++s) {
      bf16x8 af[4], bfr[3];
#pragma unroll
      for (int mf = 0; mf < 4; ++mf) {
        int r = mf * 16 + lrow;
        af[mf] = *(const bf16x8*)((const char*)xs + r * 128 +
                                  ((s * 64 + lg * 16) ^ ((r & 7) << 4)));
      }
#pragma unroll
      for (int nf = 0; nf < 3; ++nf) {
        int col = wv * 48 + nf * 16 + lrow;
        bfr[nf] = *(const bf16x8*)(Wt + (size_t)col * CB + k0 + s * 32 + lg * 8);
      }
#pragma unroll
      for (int mf = 0; mf < 4; ++mf)
#pragma unroll
        for (int nf = 0; nf < 3; ++nf)
          acc[mf][nf] = __builtin_amdgcn_mfma_f32_16x16x32_bf16(af[mf], bfr[nf], acc[mf][nf], 0, 0, 0);
    }
    __syncthreads();
  }

  unsigned short* pb = part + (size_t)ks * NROWS * 192;
#pragma unroll
  for (int mf = 0; mf < 4; ++mf)
#pragma unroll
    for (int nf = 0; nf < 3; ++nf)
#pragma unroll
      for (int r = 0; r < 4; ++r) {
        int grow = m0 + mf * 16 + lg * 4 + r;
        int j = wv * 48 + nf * 16 + lrow;
        pb[(size_t)grow * 192 + j] = f2bf(acc[mf][nf][r]);
      }
}

// ---------------- kernel 1b: fused reduce (q,k and transposed v) -------------
__global__ void reduce_qkv_kernel(const unsigned short* __restrict__ part,
                                  unsigned short* __restrict__ q, unsigned short* __restrict__ k,
                                  unsigned short* __restrict__ vT, int SK) {
  __shared__ float tr[64][17];
  if (blockIdx.x < 4096) {
    int id = blockIdx.x * 256 + threadIdx.x;
    int row = id >> 7, col = id & 127;
    float s = 0.f;
    for (int ks = 0; ks < SK; ++ks)
      s += bf2f(part[((size_t)ks * NROWS + row) * 192 + col]);
    unsigned short v = f2bf(s);
    if (col < 64) q[(size_t)row * 64 + col] = v;
    else          k[(size_t)row * 64 + (col - 64)] = v;
  } else {
    int bid = blockIdx.x - 4096;
    const int t0 = (bid & 127) * 16;
    const int b = bid >> 7;
    const int c = threadIdx.x & 63, trow = threadIdx.x >> 6;
#pragma unroll
    for (int p = 0; p < 4; ++p) {
      int tl = p * 4 + trow;
      int row = b * TB + t0 + tl;
      float s = 0.f;
      for (int ks = 0; ks < SK; ++ks)
        s += bf2f(part[((size_t)ks * NROWS + row) * 192 + 128 + c]);
      tr[c][tl] = s;
    }
    __syncthreads();
    const int h = threadIdx.x >> 2, tq = threadIdx.x & 3;
    u32x2 pk;
    pk.x = pack2bf(tr[h][tq * 4 + 0], tr[h][tq * 4 + 1]);
    pk.y = pack2bf(tr[h][tq * 4 + 2], tr[h][tq * 4 + 3]);
    *(u32x2*)(vT + ((size_t)(b * 64 + h)) * TB + t0 + tq * 4) = pk;
  }
}

// ---------------- kernel 2: causal flash attention ---------------------------
// grid (T/32, NSP, B), block 128 (2 waves x 16 Q-rows). Lane owns q-row = l&15.
// K,V staged in LDS. Partials SPLIT-MAJOR: PO[sp][row][h], Mp[sp][row], Lp[sp][row]
// -> each WG writes one dense exclusive 4KB block (no cross-WG partial lines).
__launch_bounds__(128, 4)
__global__ void attn_kernel(const unsigned short* __restrict__ q,
                            const unsigned short* __restrict__ k,
                            const unsigned short* __restrict__ vT,
                            unsigned short* __restrict__ PO, float* __restrict__ Mp,
                            float* __restrict__ Lp, int NS) {
  __shared__ __align__(16) char ksm[8192]; // K tile [64 kv][128B], swz (r&7)<<4
  __shared__ __align__(16) char vsm[8192]; // V tile [64 h][128B kv], swz (r&3)<<5
  const int tid = threadIdx.x;
  const int wv = tid >> 6, l = tid & 63;
  const int lrow = l & 15, lg = l >> 4;
  const int qt = blockIdx.x, sp = blockIdx.y, b = blockIdx.z;
  const int q0 = qt * 32;
  const int q0w = q0 + wv * 16;
  const int qrow = q0w + lrow;
  const int nb = (q0 + 32 + 63) >> 6;
  const int b0 = (sp * nb) / NS, b1 = ((sp + 1) * nb) / NS;
  const unsigned short* qb = q + (size_t)b * TB * 64;
  const char* kbb = (const char*)(k + (size_t)b * TB * 64);
  const unsigned short* vb = vT + (size_t)b * 64 * TB;

  const int krow = tid >> 3;
  const int kcol = ((tid & 7) ^ (krow & 7)) << 4;
  const int sr_base = wv * 32 + (l >> 3);
  const int si16 = l & 7;
  const int sswz = ((l >> 3) & 3) << 5;

  bf16x8 qf[2];
#pragma unroll
  for (int s = 0; s < 2; ++s)
    qf[s] = *(const bf16x8*)(qb + (size_t)qrow * 64 + s * 32 + lg * 8);

  float m = -INFINITY, lsl = 0.f;
  f32x4 o[4];
#pragma unroll
  for (int hf = 0; hf < 4; ++hf) o[hf] = (f32x4){0.f, 0.f, 0.f, 0.f};

  const float scale = 0.03608439182435161f; // 768^-0.5
  const int rswz = (lrow & 3) << 5;
  const int kswz = (lrow & 7) << 4;

  float4 kpre[4], vpre[4];
  if (b0 < b1) {
#pragma unroll
    for (int c = 0; c < 4; ++c)
      kpre[c] = *(const float4*)(kbb + (size_t)b0 * 8192 + c * 2048 + tid * 16);
#pragma unroll
    for (int j = 0; j < 4; ++j)
      vpre[j] = *(const float4*)(vb + (size_t)(sr_base + 8 * j) * TB + b0 * 64 + si16 * 8);
  }

  for (int blk = b0; blk < b1; ++blk) {
    const int kv0 = blk * 64;
    __syncthreads();
#pragma unroll
    for (int c = 0; c < 4; ++c)
      *(float4*)(ksm + c * 2048 + krow * 128 + kcol) = kpre[c];
#pragma unroll
    for (int j = 0; j < 4; ++j)
      *(float4*)(vsm + (sr_base + 8 * j) * 128 + ((si16 * 16) ^ sswz)) = vpre[j];
    if (blk + 1 < b1) {
#pragma unroll
      for (int c = 0; c < 4; ++c)
        kpre[c] = *(const float4*)(kbb + (size_t)(kv0 + 64) * 128 + c * 2048 + tid * 16);
#pragma unroll
      for (int j = 0; j < 4; ++j)
        vpre[j] = *(const float4*)(vb + (size_t)(sr_base + 8 * j) * TB + (kv0 + 64) + si16 * 8);
    }
    __syncthreads();

    f32x4 S[4];
#pragma unroll
    for (int cf = 0; cf < 4; ++cf) S[cf] = (f32x4){0.f, 0.f, 0.f, 0.f};
#pragma unroll
    for (int cf = 0; cf < 4; ++cf) {
      const char* kp = ksm + (cf * 16 + lrow) * 128;
#pragma unroll
      for (int s = 0; s < 2; ++s) {
        bf16x8 kf = *(const bf16x8*)(kp + ((s * 64 + lg * 16) ^ kswz));
        S[cf] = __builtin_amdgcn_mfma_f32_16x16x32_bf16(kf, qf[s], S[cf], 0, 0, 0);
      }
    }
    float tmx = -INFINITY;
#pragma unroll
    for (int cf = 0; cf < 4; ++cf)
#pragma unroll
      for (int r = 0; r < 4; ++r) {
        float vv = S[cf][r] * scale;
        int kvi = kv0 + cf * 16 + lg * 4 + r;
        vv = (kvi > qrow) ? -INFINITY : vv;
        S[cf][r] = vv;
        tmx = fmaxf(tmx, vv);
      }
    tmx = fmaxf(tmx, __shfl_xor(tmx, 16));
    tmx = fmaxf(tmx, __shfl_xor(tmx, 32));
    if (!__all(tmx <= m + 8.f)) {
      float mn = fmaxf(m, tmx);
      float fr = __expf(m - mn);
      lsl *= fr;
#pragma unroll
      for (int hf = 0; hf < 4; ++hf)
#pragma unroll
        for (int r = 0; r < 4; ++r) o[hf][r] *= fr;
      m = mn;
    }
    float p[4][4];
#pragma unroll
    for (int cf = 0; cf < 4; ++cf)
#pragma unroll
      for (int r = 0; r < 4; ++r) {
        float pe = __expf(S[cf][r] - m);
        p[cf][r] = pe;
        lsl += pe;
      }
    union { unsigned u[4]; bf16x8 v; } pbu[2];
#pragma unroll
    for (int s = 0; s < 2; ++s) {
      pbu[s].u[0] = pack2bf(p[2 * s][0], p[2 * s][1]);
      pbu[s].u[1] = pack2bf(p[2 * s][2], p[2 * s][3]);
      pbu[s].u[2] = pack2bf(p[2 * s + 1][0], p[2 * s + 1][1]);
      pbu[s].u[3] = pack2bf(p[2 * s + 1][2], p[2 * s + 1][3]);
    }
#pragma unroll
    for (int s = 0; s < 2; ++s)
#pragma unroll
      for (int hf = 0; hf < 4; ++hf) {
        int r = hf * 16 + lrow;
        int a1 = r * 128 + ((s * 64 + lg * 8) ^ rswz);
        u32x2 lo = *(const u32x2*)(vsm + a1);
        u32x2 hi = *(const u32x2*)(vsm + (a1 ^ 32));
        union { unsigned u[4]; bf16x8 v; } vfu;
        vfu.u[0] = lo.x; vfu.u[1] = lo.y; vfu.u[2] = hi.x; vfu.u[3] = hi.y;
        o[hf] = __builtin_amdgcn_mfma_f32_16x16x32_bf16(vfu.v, pbu[s].v, o[hf], 0, 0, 0);
      }
  }

  float ls = lsl;
  ls += __shfl_xor(ls, 16);
  ls += __shfl_xor(ls, 32);

  // SPLIT-MAJOR partial write: dense exclusive block per WG
  size_t rowg = (size_t)sp * NROWS + b * TB + qrow;
  unsigned short* pop = PO + rowg * 64 + lg * 4;
#pragma unroll
  for (int hf = 0; hf < 4; ++hf) {
    u32x2 pk;
    pk.x = pack2bf(o[hf][0], o[hf][1]);
    pk.y = pack2bf(o[hf][2], o[hf][3]);
    *(u32x2*)(pop + hf * 16) = pk;
  }
  if (lg == 0) {
    Mp[rowg] = m;
    Lp[rowg] = ls;
  }
}

// ---------------- kernel 2b: combine KV-splits (split-major layout) ----------
__global__ void attn_reduce_kernel(const unsigned short* __restrict__ PO,
                                   const float* __restrict__ Mp,
                                   const float* __restrict__ Lp,
                                   float* __restrict__ out, int NS) {
  int id = blockIdx.x * 256 + threadIdx.x;
  if (id >= NROWS * 16) return;
  int row = id >> 4, h0 = (id & 15) * 4;
  float M = -INFINITY;
  for (int s = 0; s < NS; ++s) M = fmaxf(M, Mp[(size_t)s * NROWS + row]);
  float L = 0.f;
  float a0 = 0.f, a1 = 0.f, a2 = 0.f, a3 = 0.f;
  for (int s = 0; s < NS; ++s) {
    float w = __expf(Mp[(size_t)s * NROWS + row] - M);
    L += Lp[(size_t)s * NROWS + row] * w;
    u32x2 pv = *(const u32x2*)(PO + ((size_t)s * NROWS + row) * 64 + h0);
    a0 += bf2f((unsigned short)(pv.x & 0xffff)) * w;
    a1 += bf2f((unsigned short)(pv.x >> 16)) * w;
    a2 += bf2f((unsigned short)(pv.y & 0xffff)) * w;
    a3 += bf2f((unsigned short)(pv.y >> 16)) * w;
  }
  float rL = 1.f / L;
  f32x4 r; r.x = a0 * rL; r.y = a1 * rL; r.z = a2 * rL; r.w = a3 * rL;
  *(f32x4*)(out + (size_t)row * 64 + h0) = r;
}

extern "C" void kernel_launch(void* const* d_in, const int* in_sizes, int n_in,
                              void* d_out, int out_size, void* d_ws, size_t ws_size,
                              hipStream_t stream) {
  const float* x  = (const float*)d_in[0];
  const float* Wq = (const float*)d_in[1];
  const float* Wk = (const float*)d_in[2];
  const float* Wv = (const float*)d_in[3];
  float* out = (float*)d_out;

  unsigned short* Wt = (unsigned short*)d_ws;
  unsigned short* qb = Wt + 192 * CB;
  unsigned short* kb = qb + (size_t)NROWS * 64;
  unsigned short* vT = kb + (size_t)NROWS * 64;
  char* scratch = (char*)(vT + (size_t)NROWS * 64);
  size_t used_base = (size_t)(scratch - (char*)d_ws);

  auto scratch_need = [](int SK, int NS) -> size_t {
    size_t p = (size_t)SK * NROWS * 192 * 2;
    size_t a = (size_t)NS * NROWS * 64 * 2 + (size_t)NS * NROWS * 2 * 4;
    return p > a ? p : a;
  };
  int SK = SKV, NS = NSP;
  if (used_base + scratch_need(SK, NS) > ws_size) { SK = 2; NS = 4; }
  if (used_base + scratch_need(SK, NS) > ws_size) { SK = 1; NS = 2; }

  unsigned short* part = (unsigned short*)scratch;
  unsigned short* PO = (unsigned short*)scratch;
  float* Mp = (float*)(scratch + (size_t)NS * NROWS * 64 * 2);
  float* Lp = Mp + (size_t)NS * NROWS;

  hipLaunchKernelGGL(cvt_w_kernel, dim3(12, 3), dim3(256), 0, stream,
                     Wq, Wk, Wv, Wt);
  hipLaunchKernelGGL(proj_kernel, dim3(NROWS / 64, SK), dim3(256), 0, stream,
                     x, Wt, part, CB / (64 * SK));
  hipLaunchKernelGGL(reduce_qkv_kernel, dim3(4096 + 512), dim3(256), 0, stream,
                     part, qb, kb, vT, SK);
  hipLaunchKernelGGL(attn_kernel, dim3(TB / 32, NS, NB), dim3(128), 0, stream,
                     qb, kb, vT, PO, Mp, Lp, NS);
  hipLaunchKernelGGL(attn_reduce_kernel, dim3((NROWS * 16) / 256), dim3(256), 0, stream,
                     PO, Mp, Lp, out, NS);
}

// Round 10
// 70.494 us; speedup vs baseline: 1.1733x; 1.1733x over previous
//
#include <hip/hip_runtime.h>
#include <math.h>

// B=4, T=2048, C=768, H=64
#define TB 2048
#define CB 768
#define NB 4
#define NROWS (NB * TB) // 8192
#define SKV 6           // proj K-split
#define NSMAX 32        // max KV splits per row (T/64)
#define WGPB 2112       // per-batch attn WGs: sum_{i=0..127} ceil((i+1)/4)

typedef __attribute__((ext_vector_type(8))) short bf16x8;
typedef __attribute__((ext_vector_type(4))) float f32x4;
typedef __attribute__((ext_vector_type(2))) float f32x2;
typedef __attribute__((ext_vector_type(2))) unsigned int u32x2;
typedef __attribute__((ext_vector_type(4))) unsigned int u32x4;

__device__ inline unsigned short f2bf(float f) {
  union { float f; unsigned u; } v; v.f = f;
  unsigned r = v.u + 0x7FFFu + ((v.u >> 16) & 1u);
  return (unsigned short)(r >> 16);
}
__device__ inline unsigned pack2bf(float a, float b) {
  return (unsigned)f2bf(a) | ((unsigned)f2bf(b) << 16);
}
__device__ inline float bf2f(unsigned short u) {
  union { unsigned u; float f; } v; v.u = (unsigned)u << 16; return v.f;
}

// ---------------- kernel 0: weights fp32 [C][64] x3 -> Wt bf16 [192][768] ----
__global__ void cvt_w_kernel(const float* __restrict__ Wq, const float* __restrict__ Wk,
                             const float* __restrict__ Wv, unsigned short* __restrict__ Wt) {
  __shared__ float tw[64][65];
  const float* W = (blockIdx.y == 0) ? Wq : (blockIdx.y == 1) ? Wk : Wv;
  const int c0 = blockIdx.x * 64;
  const int row = threadIdx.x >> 2, seg = threadIdx.x & 3;
#pragma unroll
  for (int i = 0; i < 4; ++i) {
    float4 f = *(const float4*)(W + (size_t)(c0 + row) * 64 + seg * 16 + i * 4);
    tw[row][seg * 16 + i * 4 + 0] = f.x;
    tw[row][seg * 16 + i * 4 + 1] = f.y;
    tw[row][seg * 16 + i * 4 + 2] = f.z;
    tw[row][seg * 16 + i * 4 + 3] = f.w;
  }
  __syncthreads();
  const int j = threadIdx.x >> 2, cq = threadIdx.x & 3;
  unsigned short* dst = Wt + (size_t)(blockIdx.y * 64 + j) * CB + c0 + cq * 16;
  u32x4 ua, ub;
#pragma unroll
  for (int i = 0; i < 4; ++i) ua[i] = pack2bf(tw[cq * 16 + 2 * i][j], tw[cq * 16 + 2 * i + 1][j]);
#pragma unroll
  for (int i = 0; i < 4; ++i) ub[i] = pack2bf(tw[cq * 16 + 8 + 2 * i][j], tw[cq * 16 + 9 + 2 * i][j]);
  *(u32x4*)dst = ua;
  *(u32x4*)(dst + 8) = ub;
}

// ---------------- kernel 1: QKV projection GEMM, K-split ---------------------
__launch_bounds__(256)
__global__ void proj_kernel(const float* __restrict__ x, const unsigned short* __restrict__ Wt,
                            unsigned short* __restrict__ part, int ksteps) {
  __shared__ __align__(16) unsigned short xs[64 * 64];
  const int tid = threadIdx.x;
  const int wv = tid >> 6;
  const int l = tid & 63;
  const int lrow = l & 15, lg = l >> 4;
  const int m0 = blockIdx.x * 64;
  const int ks = blockIdx.y;
  const int kbase = ks * ksteps * 64;
  const int srow = tid >> 2;
  const int sq = tid & 3;
  const float* xp = x + (size_t)(m0 + srow) * CB + sq * 16;

  f32x4 acc[4][3];
#pragma unroll
  for (int a = 0; a < 4; ++a)
#pragma unroll
    for (int n = 0; n < 3; ++n) acc[a][n] = (f32x4){0.f, 0.f, 0.f, 0.f};

  for (int kk = 0; kk < ksteps; ++kk) {
    int k0 = kbase + kk * 64;
    bf16x8 c0, c1;
#pragma unroll
    for (int i = 0; i < 2; ++i) {
      float4 f = *(const float4*)(xp + k0 + 4 * i);
      c0[4 * i + 0] = (short)f2bf(f.x); c0[4 * i + 1] = (short)f2bf(f.y);
      c0[4 * i + 2] = (short)f2bf(f.z); c0[4 * i + 3] = (short)f2bf(f.w);
    }
#pragma unroll
    for (int i = 0; i < 2; ++i) {
      float4 f = *(const float4*)(xp + k0 + 8 + 4 * i);
      c1[4 * i + 0] = (short)f2bf(f.x); c1[4 * i + 1] = (short)f2bf(f.y);
      c1[4 * i + 2] = (short)f2bf(f.z); c1[4 * i + 3] = (short)f2bf(f.w);
    }
    {
      char* base = (char*)xs + srow * 128;
      int swz = (srow & 7) << 4;
      *(bf16x8*)(base + ((sq * 32 + 0) ^ swz)) = c0;
      *(bf16x8*)(base + ((sq * 32 + 16) ^ swz)) = c1;
    }
    __syncthreads();

#pragma unroll
    for (int s = 0; s < 2; ++s) {
      bf16x8 af[4], bfr[3];
#pragma unroll
      for (int mf = 0; mf < 4; ++mf) {
        int r = mf * 16 + lrow;
        af[mf] = *(const bf16x8*)((const char*)xs + r * 128 +
                                  ((s * 64 + lg * 16) ^ ((r & 7) << 4)));
      }
#pragma unroll
      for (int nf = 0; nf < 3; ++nf) {
        int col = wv * 48 + nf * 16 + lrow;
        bfr[nf] = *(const bf16x8*)(Wt + (size_t)col * CB + k0 + s * 32 + lg * 8);
      }
#pragma unroll
      for (int mf = 0; mf < 4; ++mf)
#pragma unroll
        for (int nf = 0; nf < 3; ++nf)
          acc[mf][nf] = __builtin_amdgcn_mfma_f32_16x16x32_bf16(af[mf], bfr[nf], acc[mf][nf], 0, 0, 0);
    }
    __syncthreads();
  }

  unsigned short* pb = part + (size_t)ks * NROWS * 192;
#pragma unroll
  for (int mf = 0; mf < 4; ++mf)
#pragma unroll
    for (int nf = 0; nf < 3; ++nf)
#pragma unroll
      for (int r = 0; r < 4; ++r) {
        int grow = m0 + mf * 16 + lg * 4 + r;
        int j = wv * 48 + nf * 16 + lrow;
        pb[(size_t)grow * 192 + j] = f2bf(acc[mf][nf][r]);
      }
}

// ---------------- kernel 1b: fused reduce (q,k and transposed v) -------------
__global__ void reduce_qkv_kernel(const unsigned short* __restrict__ part,
                                  unsigned short* __restrict__ q, unsigned short* __restrict__ k,
                                  unsigned short* __restrict__ vT, int SK) {
  __shared__ float tr[64][17];
  if (blockIdx.x < 4096) {
    int id = blockIdx.x * 256 + threadIdx.x;
    int row = id >> 7, col = id & 127;
    float s = 0.f;
    for (int ks = 0; ks < SK; ++ks)
      s += bf2f(part[((size_t)ks * NROWS + row) * 192 + col]);
    unsigned short v = f2bf(s);
    if (col < 64) q[(size_t)row * 64 + col] = v;
    else          k[(size_t)row * 64 + (col - 64)] = v;
  } else {
    int bid = blockIdx.x - 4096;
    const int t0 = (bid & 127) * 16;
    const int b = bid >> 7;
    const int c = threadIdx.x & 63, trow = threadIdx.x >> 6;
#pragma unroll
    for (int p = 0; p < 4; ++p) {
      int tl = p * 4 + trow;
      int row = b * TB + t0 + tl;
      float s = 0.f;
      for (int ks = 0; ks < SK; ++ks)
        s += bf2f(part[((size_t)ks * NROWS + row) * 192 + 128 + c]);
      tr[c][tl] = s;
    }
    __syncthreads();
    const int h = threadIdx.x >> 2, tq = threadIdx.x & 3;
    u32x2 pk;
    pk.x = pack2bf(tr[h][tq * 4 + 0], tr[h][tq * 4 + 1]);
    pk.y = pack2bf(tr[h][tq * 4 + 2], tr[h][tq * 4 + 3]);
    *(u32x2*)(vT + ((size_t)(b * 64 + h)) * TB + t0 + tq * 4) = pk;
  }
}

// ---------------- kernel 2: causal attention, ONE KV-block per 1-wave WG -----
// grid (WGPB, B), block 64. WG w -> (a = tile group, rt = tile-in-group, blk).
// tile i = 4a+rt owns q-rows [16i,16i+16); blocks per tile = a+1; blk in [0,a].
// No loop, no barrier (wave-private V LDS), no online softmax (single block).
__launch_bounds__(64, 4)
__global__ void attn_kernel(const unsigned short* __restrict__ q,
                            const unsigned short* __restrict__ k,
                            const unsigned short* __restrict__ vT,
                            unsigned short* __restrict__ PO, float* __restrict__ Mp,
                            float* __restrict__ Lp) {
  __shared__ __align__(16) char vsm[8192]; // V tile [64 h][128B kv], swz (r&3)<<5
  const int l = threadIdx.x;
  const int lrow = l & 15, lg = l >> 4;
  const int b = blockIdx.y;
  const int w = blockIdx.x;

  // decode triangular index: a = floor((sqrt(1+2w)-1)/2), with integer fixup
  int a = (int)((sqrtf((float)(1 + 2 * w)) - 1.f) * 0.5f);
  while (2 * (a + 1) * (a + 2) <= w) ++a;
  while (2 * a * (a + 1) > w) --a;
  const int rem = w - 2 * a * (a + 1);
  const int rt = rem / (a + 1);
  const int blk = rem - rt * (a + 1);
  const int q0 = (4 * a + rt) * 16;
  const int qrow = q0 + lrow;
  const int kv0 = blk * 64;
  const bool last = (blk == a);

  const unsigned short* qb = q + (size_t)b * TB * 64;
  const unsigned short* kb = k + (size_t)b * TB * 64;
  const unsigned short* vb = vT + (size_t)b * 64 * TB;

  // --- issue V staging loads first (latency hides under QK) ---
  const int sr = l >> 3, si16 = l & 7;
  float4 vg[8];
#pragma unroll
  for (int j = 0; j < 8; ++j)
    vg[j] = *(const float4*)(vb + (size_t)(j * 8 + sr) * TB + kv0 + si16 * 8);

  // --- Q fragment ---
  bf16x8 qf[2];
#pragma unroll
  for (int s = 0; s < 2; ++s)
    qf[s] = *(const bf16x8*)(qb + (size_t)qrow * 64 + s * 32 + lg * 8);

  // --- QK^T, K direct from global ---
  f32x4 S[4];
#pragma unroll
  for (int cf = 0; cf < 4; ++cf) S[cf] = (f32x4){0.f, 0.f, 0.f, 0.f};
#pragma unroll
  for (int cf = 0; cf < 4; ++cf) {
    const unsigned short* kp = kb + (size_t)(kv0 + cf * 16 + lrow) * 64 + lg * 8;
#pragma unroll
    for (int s = 0; s < 2; ++s) {
      bf16x8 kf = *(const bf16x8*)(kp + s * 32);
      S[cf] = __builtin_amdgcn_mfma_f32_16x16x32_bf16(kf, qf[s], S[cf], 0, 0, 0);
    }
  }

  const float scale = 0.03608439182435161f; // 768^-0.5
  float tmx = -INFINITY;
#pragma unroll
  for (int cf = 0; cf < 4; ++cf)
#pragma unroll
    for (int r = 0; r < 4; ++r) {
      float vv = S[cf][r] * scale;
      if (last) {
        int kvi = kv0 + cf * 16 + lg * 4 + r;
        vv = (kvi > qrow) ? -INFINITY : vv;
      }
      S[cf][r] = vv;
      tmx = fmaxf(tmx, vv);
    }
  tmx = fmaxf(tmx, __shfl_xor(tmx, 16));
  tmx = fmaxf(tmx, __shfl_xor(tmx, 32)); // row max

  float lsl = 0.f;
  float p[4][4];
#pragma unroll
  for (int cf = 0; cf < 4; ++cf)
#pragma unroll
    for (int r = 0; r < 4; ++r) {
      float pe = __expf(S[cf][r] - tmx);
      p[cf][r] = pe;
      lsl += pe;
    }
  union { unsigned u[4]; bf16x8 v; } pbu[2];
#pragma unroll
  for (int s = 0; s < 2; ++s) {
    pbu[s].u[0] = pack2bf(p[2 * s][0], p[2 * s][1]);
    pbu[s].u[1] = pack2bf(p[2 * s][2], p[2 * s][3]);
    pbu[s].u[2] = pack2bf(p[2 * s + 1][0], p[2 * s + 1][1]);
    pbu[s].u[3] = pack2bf(p[2 * s + 1][2], p[2 * s + 1][3]);
  }

  // --- write V tile to LDS (swizzled); same-wave, no barrier ---
#pragma unroll
  for (int j = 0; j < 8; ++j) {
    int r = j * 8 + sr;
    *(float4*)(vsm + r * 128 + ((si16 * 16) ^ ((r & 3) << 5))) = vg[j];
  }

  // --- PV from LDS, kv-permutation matching P's lane order ---
  f32x4 o[4];
#pragma unroll
  for (int hf = 0; hf < 4; ++hf) o[hf] = (f32x4){0.f, 0.f, 0.f, 0.f};
  const int rswz = (lrow & 3) << 5;
#pragma unroll
  for (int s = 0; s < 2; ++s)
#pragma unroll
    for (int hf = 0; hf < 4; ++hf) {
      int r = hf * 16 + lrow;
      int a1 = r * 128 + ((s * 64 + lg * 8) ^ rswz);
      u32x2 lo = *(const u32x2*)(vsm + a1);
      u32x2 hi = *(const u32x2*)(vsm + (a1 ^ 32));
      union { unsigned u[4]; bf16x8 v; } vfu;
      vfu.u[0] = lo.x; vfu.u[1] = lo.y; vfu.u[2] = hi.x; vfu.u[3] = hi.y;
      o[hf] = __builtin_amdgcn_mfma_f32_16x16x32_bf16(vfu.v, pbu[s].v, o[hf], 0, 0, 0);
    }

  float ls = lsl;
  ls += __shfl_xor(ls, 16);
  ls += __shfl_xor(ls, 32);

  // split-major partial write, plane = blk
  size_t rowg = (size_t)blk * NROWS + b * TB + qrow;
  unsigned short* pop = PO + rowg * 64 + lg * 4;
#pragma unroll
  for (int hf = 0; hf < 4; ++hf) {
    u32x2 pk;
    pk.x = pack2bf(o[hf][0], o[hf][1]);
    pk.y = pack2bf(o[hf][2], o[hf][3]);
    *(u32x2*)(pop + hf * 16) = pk;
  }
  if (lg == 0) {
    Mp[rowg] = tmx;
    Lp[rowg] = ls;
  }
}

// ---------------- kernel 2b: combine per-row variable splits -----------------
__global__ void attn_reduce_kernel(const unsigned short* __restrict__ PO,
                                   const float* __restrict__ Mp,
                                   const float* __restrict__ Lp,
                                   float* __restrict__ out) {
  int id = blockIdx.x * 256 + threadIdx.x;
  if (id >= NROWS * 16) return;
  int row = id >> 4, h0 = (id & 15) * 4;
  int t = row & (TB - 1);
  int ns = (t >> 6) + 1; // splits for this row
  float M = -INFINITY;
  for (int s = 0; s < ns; ++s) M = fmaxf(M, Mp[(size_t)s * NROWS + row]);
  float L = 0.f;
  float a0 = 0.f, a1 = 0.f, a2 = 0.f, a3 = 0.f;
  for (int s = 0; s < ns; ++s) {
    float w = __expf(Mp[(size_t)s * NROWS + row] - M);
    L += Lp[(size_t)s * NROWS + row] * w;
    u32x2 pv = *(const u32x2*)(PO + ((size_t)s * NROWS + row) * 64 + h0);
    a0 += bf2f((unsigned short)(pv.x & 0xffff)) * w;
    a1 += bf2f((unsigned short)(pv.x >> 16)) * w;
    a2 += bf2f((unsigned short)(pv.y & 0xffff)) * w;
    a3 += bf2f((unsigned short)(pv.y >> 16)) * w;
  }
  float rL = 1.f / L;
  f32x4 r; r.x = a0 * rL; r.y = a1 * rL; r.z = a2 * rL; r.w = a3 * rL;
  *(f32x4*)(out + (size_t)row * 64 + h0) = r;
}

extern "C" void kernel_launch(void* const* d_in, const int* in_sizes, int n_in,
                              void* d_out, int out_size, void* d_ws, size_t ws_size,
                              hipStream_t stream) {
  const float* x  = (const float*)d_in[0];
  const float* Wq = (const float*)d_in[1];
  const float* Wk = (const float*)d_in[2];
  const float* Wv = (const float*)d_in[3];
  float* out = (float*)d_out;

  unsigned short* Wt = (unsigned short*)d_ws;
  unsigned short* qb = Wt + 192 * CB;
  unsigned short* kb = qb + (size_t)NROWS * 64;
  unsigned short* vT = kb + (size_t)NROWS * 64;
  char* scratch = (char*)(vT + (size_t)NROWS * 64);

  int SK = SKV;
  unsigned short* part = (unsigned short*)scratch;              // SK*8192*192*2 = 18.9 MB
  unsigned short* PO = (unsigned short*)scratch;                // 32*8192*128 B = 33.6 MB
  float* Mp = (float*)(scratch + (size_t)NSMAX * NROWS * 64 * 2);
  float* Lp = Mp + (size_t)NSMAX * NROWS;

  hipLaunchKernelGGL(cvt_w_kernel, dim3(12, 3), dim3(256), 0, stream,
                     Wq, Wk, Wv, Wt);
  hipLaunchKernelGGL(proj_kernel, dim3(NROWS / 64, SK), dim3(256), 0, stream,
                     x, Wt, part, CB / (64 * SK));
  hipLaunchKernelGGL(reduce_qkv_kernel, dim3(4096 + 512), dim3(256), 0, stream,
                     part, qb, kb, vT, SK);
  hipLaunchKernelGGL(attn_kernel, dim3(WGPB, NB), dim3(64), 0, stream,
                     qb, kb, vT, PO, Mp, Lp);
  hipLaunchKernelGGL(attn_reduce_kernel, dim3((NROWS * 16) / 256), dim3(256), 0, stream,
                     PO, Mp, Lp, out);
}

// Round 11
// 64.643 us; speedup vs baseline: 1.2795x; 1.0905x over previous
//
#include <hip/hip_runtime.h>
#include <math.h>

// B=4, T=2048, C=768, H=64
#define TB 2048
#define CB 768
#define NB 4
#define NROWS (NB * TB) // 8192
#define SKV 6           // proj K-split
#define NSMAX 32        // max KV splits per row (T/64)
#define WGPB 528        // per-batch attn WGs: sum_{g=0..31} (g+1)

typedef __attribute__((ext_vector_type(8))) short bf16x8;
typedef __attribute__((ext_vector_type(4))) float f32x4;
typedef __attribute__((ext_vector_type(2))) float f32x2;
typedef __attribute__((ext_vector_type(2))) unsigned int u32x2;
typedef __attribute__((ext_vector_type(4))) unsigned int u32x4;

__device__ inline unsigned short f2bf(float f) {
  union { float f; unsigned u; } v; v.f = f;
  unsigned r = v.u + 0x7FFFu + ((v.u >> 16) & 1u);
  return (unsigned short)(r >> 16);
}
__device__ inline unsigned pack2bf(float a, float b) {
  return (unsigned)f2bf(a) | ((unsigned)f2bf(b) << 16);
}
__device__ inline float bf2f(unsigned short u) {
  union { unsigned u; float f; } v; v.u = (unsigned)u << 16; return v.f;
}

// ---------------- kernel 0: weights fp32 [C][64] x3 -> Wt bf16 [192][768] ----
__global__ void cvt_w_kernel(const float* __restrict__ Wq, const float* __restrict__ Wk,
                             const float* __restrict__ Wv, unsigned short* __restrict__ Wt) {
  __shared__ float tw[64][65];
  const float* W = (blockIdx.y == 0) ? Wq : (blockIdx.y == 1) ? Wk : Wv;
  const int c0 = blockIdx.x * 64;
  const int row = threadIdx.x >> 2, seg = threadIdx.x & 3;
#pragma unroll
  for (int i = 0; i < 4; ++i) {
    float4 f = *(const float4*)(W + (size_t)(c0 + row) * 64 + seg * 16 + i * 4);
    tw[row][seg * 16 + i * 4 + 0] = f.x;
    tw[row][seg * 16 + i * 4 + 1] = f.y;
    tw[row][seg * 16 + i * 4 + 2] = f.z;
    tw[row][seg * 16 + i * 4 + 3] = f.w;
  }
  __syncthreads();
  const int j = threadIdx.x >> 2, cq = threadIdx.x & 3;
  unsigned short* dst = Wt + (size_t)(blockIdx.y * 64 + j) * CB + c0 + cq * 16;
  u32x4 ua, ub;
#pragma unroll
  for (int i = 0; i < 4; ++i) ua[i] = pack2bf(tw[cq * 16 + 2 * i][j], tw[cq * 16 + 2 * i + 1][j]);
#pragma unroll
  for (int i = 0; i < 4; ++i) ub[i] = pack2bf(tw[cq * 16 + 8 + 2 * i][j], tw[cq * 16 + 9 + 2 * i][j]);
  *(u32x4*)dst = ua;
  *(u32x4*)(dst + 8) = ub;
}

// ---------------- kernel 1: QKV projection GEMM, K-split ---------------------
__launch_bounds__(256)
__global__ void proj_kernel(const float* __restrict__ x, const unsigned short* __restrict__ Wt,
                            unsigned short* __restrict__ part, int ksteps) {
  __shared__ __align__(16) unsigned short xs[64 * 64];
  const int tid = threadIdx.x;
  const int wv = tid >> 6;
  const int l = tid & 63;
  const int lrow = l & 15, lg = l >> 4;
  const int m0 = blockIdx.x * 64;
  const int ks = blockIdx.y;
  const int kbase = ks * ksteps * 64;
  const int srow = tid >> 2;
  const int sq = tid & 3;
  const float* xp = x + (size_t)(m0 + srow) * CB + sq * 16;

  f32x4 acc[4][3];
#pragma unroll
  for (int a = 0; a < 4; ++a)
#pragma unroll
    for (int n = 0; n < 3; ++n) acc[a][n] = (f32x4){0.f, 0.f, 0.f, 0.f};

  for (int kk = 0; kk < ksteps; ++kk) {
    int k0 = kbase + kk * 64;
    bf16x8 c0, c1;
#pragma unroll
    for (int i = 0; i < 2; ++i) {
      float4 f = *(const float4*)(xp + k0 + 4 * i);
      c0[4 * i + 0] = (short)f2bf(f.x); c0[4 * i + 1] = (short)f2bf(f.y);
      c0[4 * i + 2] = (short)f2bf(f.z); c0[4 * i + 3] = (short)f2bf(f.w);
    }
#pragma unroll
    for (int i = 0; i < 2; ++i) {
      float4 f = *(const float4*)(xp + k0 + 8 + 4 * i);
      c1[4 * i + 0] = (short)f2bf(f.x); c1[4 * i + 1] = (short)f2bf(f.y);
      c1[4 * i + 2] = (short)f2bf(f.z); c1[4 * i + 3] = (short)f2bf(f.w);
    }
    {
      char* base = (char*)xs + srow * 128;
      int swz = (srow & 7) << 4;
      *(bf16x8*)(base + ((sq * 32 + 0) ^ swz)) = c0;
      *(bf16x8*)(base + ((sq * 32 + 16) ^ swz)) = c1;
    }
    __syncthreads();

#pragma unroll
    for (int s = 0; s < 2; ++s) {
      bf16x8 af[4], bfr[3];
#pragma unroll
      for (int mf = 0; mf < 4; ++mf) {
        int r = mf * 16 + lrow;
        af[mf] = *(const bf16x8*)((const char*)xs + r * 128 +
                                  ((s * 64 + lg * 16) ^ ((r & 7) << 4)));
      }
#pragma unroll
      for (int nf = 0; nf < 3; ++nf) {
        int col = wv * 48 + nf * 16 + lrow;
        bfr[nf] = *(const bf16x8*)(Wt + (size_t)col * CB + k0 + s * 32 + lg * 8);
      }
#pragma unroll
      for (int mf = 0; mf < 4; ++mf)
#pragma unroll
        for (int nf = 0; nf < 3; ++nf)
          acc[mf][nf] = __builtin_amdgcn_mfma_f32_16x16x32_bf16(af[mf], bfr[nf], acc[mf][nf], 0, 0, 0);
    }
    __syncthreads();
  }

  unsigned short* pb = part + (size_t)ks * NROWS * 192;
#pragma unroll
  for (int mf = 0; mf < 4; ++mf)
#pragma unroll
    for (int nf = 0; nf < 3; ++nf)
#pragma unroll
      for (int r = 0; r < 4; ++r) {
        int grow = m0 + mf * 16 + lg * 4 + r;
        int j = wv * 48 + nf * 16 + lrow;
        pb[(size_t)grow * 192 + j] = f2bf(acc[mf][nf][r]);
      }
}

// ---------------- kernel 1b: fused reduce (q,k and transposed v) -------------
__global__ void reduce_qkv_kernel(const unsigned short* __restrict__ part,
                                  unsigned short* __restrict__ q, unsigned short* __restrict__ k,
                                  unsigned short* __restrict__ vT, int SK) {
  __shared__ float tr[64][17];
  if (blockIdx.x < 4096) {
    int id = blockIdx.x * 256 + threadIdx.x;
    int row = id >> 7, col = id & 127;
    float s = 0.f;
    for (int ks = 0; ks < SK; ++ks)
      s += bf2f(part[((size_t)ks * NROWS + row) * 192 + col]);
    unsigned short v = f2bf(s);
    if (col < 64) q[(size_t)row * 64 + col] = v;
    else          k[(size_t)row * 64 + (col - 64)] = v;
  } else {
    int bid = blockIdx.x - 4096;
    const int t0 = (bid & 127) * 16;
    const int b = bid >> 7;
    const int c = threadIdx.x & 63, trow = threadIdx.x >> 6;
#pragma unroll
    for (int p = 0; p < 4; ++p) {
      int tl = p * 4 + trow;
      int row = b * TB + t0 + tl;
      float s = 0.f;
      for (int ks = 0; ks < SK; ++ks)
        s += bf2f(part[((size_t)ks * NROWS + row) * 192 + 128 + c]);
      tr[c][tl] = s;
    }
    __syncthreads();
    const int h = threadIdx.x >> 2, tq = threadIdx.x & 3;
    u32x2 pk;
    pk.x = pack2bf(tr[h][tq * 4 + 0], tr[h][tq * 4 + 1]);
    pk.y = pack2bf(tr[h][tq * 4 + 2], tr[h][tq * 4 + 3]);
    *(u32x2*)(vT + ((size_t)(b * 64 + h)) * TB + t0 + tq * 4) = pk;
  }
}

// ---------------- kernel 2: causal attention, 4 Q-tiles share one KV block ---
// grid (WGPB, B), block 256 (4 waves). WG w -> (g = tile group, blk in [0,g]).
// Tiles {4g..4g+3} (wave wid handles tile 4g+wid, rows 16*(4g+wid)..+15).
// WG stages K block + V block in LDS ONCE; each wave computes its tile.
// No loop; single barrier; split-major partials, plane = blk.
__launch_bounds__(256)
__global__ void attn_kernel(const unsigned short* __restrict__ q,
                            const unsigned short* __restrict__ k,
                            const unsigned short* __restrict__ vT,
                            unsigned short* __restrict__ PO, float* __restrict__ Mp,
                            float* __restrict__ Lp) {
  __shared__ __align__(16) char ksm[8192]; // K tile [64 kv][128B], swz (r&7)<<4
  __shared__ __align__(16) char vsm[8192]; // V tile [64 h][128B kv], swz (r&3)<<5
  const int tid = threadIdx.x;
  const int wid = tid >> 6, l = tid & 63;
  const int lrow = l & 15, lg = l >> 4;
  const int b = blockIdx.y;
  const int w = blockIdx.x;

  // decode triangular index: g s.t. g(g+1)/2 <= w < (g+1)(g+2)/2
  int g = (int)((sqrtf((float)(8 * w + 1)) - 1.f) * 0.5f);
  while ((g + 1) * (g + 2) / 2 <= w) ++g;
  while (g * (g + 1) / 2 > w) --g;
  const int blk = w - g * (g + 1) / 2;
  const int kv0 = blk * 64;
  const bool last = (blk == g);
  const int qrow = (4 * g + wid) * 16 + lrow;

  const unsigned short* qb = q + (size_t)b * TB * 64;
  const char* kbb = (const char*)(k + (size_t)b * TB * 64);
  const unsigned short* vb = vT + (size_t)b * 64 * TB;

  // --- cooperative staging: K (flat 8KB) + V (64 rows x 128B), 32B/thread each
  const int srow = tid >> 2;            // 0..63
  const int sc = (tid & 3) * 32;        // byte offset within 128B row
  float4 kg0 = *(const float4*)(kbb + (size_t)kv0 * 128 + tid * 32);
  float4 kg1 = *(const float4*)(kbb + (size_t)kv0 * 128 + tid * 32 + 16);
  const char* vrow = (const char*)(vb + (size_t)srow * TB + kv0);
  float4 vg0 = *(const float4*)(vrow + sc);
  float4 vg1 = *(const float4*)(vrow + sc + 16);

  bf16x8 qf[2];
#pragma unroll
  for (int s = 0; s < 2; ++s)
    qf[s] = *(const bf16x8*)(qb + (size_t)qrow * 64 + s * 32 + lg * 8);

  {
    const int kswz_w = (srow & 7) << 4;
    *(float4*)(ksm + srow * 128 + ((sc + 0) ^ kswz_w)) = kg0;
    *(float4*)(ksm + srow * 128 + ((sc + 16) ^ kswz_w)) = kg1;
    const int vswz_w = (srow & 3) << 5;
    *(float4*)(vsm + srow * 128 + ((sc + 0) ^ vswz_w)) = vg0;
    *(float4*)(vsm + srow * 128 + ((sc + 16) ^ vswz_w)) = vg1;
  }
  __syncthreads();

  // --- QK^T from LDS ---
  const int kswz = (lrow & 7) << 4;
  f32x4 S[4];
#pragma unroll
  for (int cf = 0; cf < 4; ++cf) S[cf] = (f32x4){0.f, 0.f, 0.f, 0.f};
#pragma unroll
  for (int cf = 0; cf < 4; ++cf) {
    const char* kp = ksm + (cf * 16 + lrow) * 128;
#pragma unroll
    for (int s = 0; s < 2; ++s) {
      bf16x8 kf = *(const bf16x8*)(kp + ((s * 64 + lg * 16) ^ kswz));
      S[cf] = __builtin_amdgcn_mfma_f32_16x16x32_bf16(kf, qf[s], S[cf], 0, 0, 0);
    }
  }

  const float scale = 0.03608439182435161f; // 768^-0.5
  float tmx = -INFINITY;
#pragma unroll
  for (int cf = 0; cf < 4; ++cf)
#pragma unroll
    for (int r = 0; r < 4; ++r) {
      float vv = S[cf][r] * scale;
      if (last) {
        int kvi = kv0 + cf * 16 + lg * 4 + r;
        vv = (kvi > qrow) ? -INFINITY : vv;
      }
      S[cf][r] = vv;
      tmx = fmaxf(tmx, vv);
    }
  tmx = fmaxf(tmx, __shfl_xor(tmx, 16));
  tmx = fmaxf(tmx, __shfl_xor(tmx, 32)); // row max

  float lsl = 0.f;
  float p[4][4];
#pragma unroll
  for (int cf = 0; cf < 4; ++cf)
#pragma unroll
    for (int r = 0; r < 4; ++r) {
      float pe = __expf(S[cf][r] - tmx);
      p[cf][r] = pe;
      lsl += pe;
    }
  union { unsigned u[4]; bf16x8 v; } pbu[2];
#pragma unroll
  for (int s = 0; s < 2; ++s) {
    pbu[s].u[0] = pack2bf(p[2 * s][0], p[2 * s][1]);
    pbu[s].u[1] = pack2bf(p[2 * s][2], p[2 * s][3]);
    pbu[s].u[2] = pack2bf(p[2 * s + 1][0], p[2 * s + 1][1]);
    pbu[s].u[3] = pack2bf(p[2 * s + 1][2], p[2 * s + 1][3]);
  }

  // --- PV from LDS, kv-permutation matching P's lane order ---
  f32x4 o[4];
#pragma unroll
  for (int hf = 0; hf < 4; ++hf) o[hf] = (f32x4){0.f, 0.f, 0.f, 0.f};
  const int rswz = (lrow & 3) << 5;
#pragma unroll
  for (int s = 0; s < 2; ++s)
#pragma unroll
    for (int hf = 0; hf < 4; ++hf) {
      int r = hf * 16 + lrow;
      int a1 = r * 128 + ((s * 64 + lg * 8) ^ rswz);
      u32x2 lo = *(const u32x2*)(vsm + a1);
      u32x2 hi = *(const u32x2*)(vsm + (a1 ^ 32));
      union { unsigned u[4]; bf16x8 v; } vfu;
      vfu.u[0] = lo.x; vfu.u[1] = lo.y; vfu.u[2] = hi.x; vfu.u[3] = hi.y;
      o[hf] = __builtin_amdgcn_mfma_f32_16x16x32_bf16(vfu.v, pbu[s].v, o[hf], 0, 0, 0);
    }

  float ls = lsl;
  ls += __shfl_xor(ls, 16);
  ls += __shfl_xor(ls, 32);

  // split-major partial write, plane = blk
  size_t rowg = (size_t)blk * NROWS + b * TB + qrow;
  unsigned short* pop = PO + rowg * 64 + lg * 4;
#pragma unroll
  for (int hf = 0; hf < 4; ++hf) {
    u32x2 pk;
    pk.x = pack2bf(o[hf][0], o[hf][1]);
    pk.y = pack2bf(o[hf][2], o[hf][3]);
    *(u32x2*)(pop + hf * 16) = pk;
  }
  if (lg == 0) {
    Mp[rowg] = tmx;
    Lp[rowg] = ls;
  }
}

// ---------------- kernel 2b: combine per-row variable splits -----------------
__global__ void attn_reduce_kernel(const unsigned short* __restrict__ PO,
                                   const float* __restrict__ Mp,
                                   const float* __restrict__ Lp,
                                   float* __restrict__ out) {
  int id = blockIdx.x * 256 + threadIdx.x;
  if (id >= NROWS * 16) return;
  int row = id >> 4, h0 = (id & 15) * 4;
  int t = row & (TB - 1);
  int ns = (t >> 6) + 1; // splits for this row
  float M = -INFINITY;
  for (int s = 0; s < ns; ++s) M = fmaxf(M, Mp[(size_t)s * NROWS + row]);
  float L = 0.f;
  float a0 = 0.f, a1 = 0.f, a2 = 0.f, a3 = 0.f;
  for (int s = 0; s < ns; ++s) {
    float w = __expf(Mp[(size_t)s * NROWS + row] - M);
    L += Lp[(size_t)s * NROWS + row] * w;
    u32x2 pv = *(const u32x2*)(PO + ((size_t)s * NROWS + row) * 64 + h0);
    a0 += bf2f((unsigned short)(pv.x & 0xffff)) * w;
    a1 += bf2f((unsigned short)(pv.x >> 16)) * w;
    a2 += bf2f((unsigned short)(pv.y & 0xffff)) * w;
    a3 += bf2f((unsigned short)(pv.y >> 16)) * w;
  }
  float rL = 1.f / L;
  f32x4 r; r.x = a0 * rL; r.y = a1 * rL; r.z = a2 * rL; r.w = a3 * rL;
  *(f32x4*)(out + (size_t)row * 64 + h0) = r;
}

extern "C" void kernel_launch(void* const* d_in, const int* in_sizes, int n_in,
                              void* d_out, int out_size, void* d_ws, size_t ws_size,
                              hipStream_t stream) {
  const float* x  = (const float*)d_in[0];
  const float* Wq = (const float*)d_in[1];
  const float* Wk = (const float*)d_in[2];
  const float* Wv = (const float*)d_in[3];
  float* out = (float*)d_out;

  unsigned short* Wt = (unsigned short*)d_ws;
  unsigned short* qb = Wt + 192 * CB;
  unsigned short* kb = qb + (size_t)NROWS * 64;
  unsigned short* vT = kb + (size_t)NROWS * 64;
  char* scratch = (char*)(vT + (size_t)NROWS * 64);

  int SK = SKV;
  unsigned short* part = (unsigned short*)scratch;              // SK*8192*192*2 = 18.9 MB
  unsigned short* PO = (unsigned short*)scratch;                // 32*8192*128 B = 33.6 MB
  float* Mp = (float*)(scratch + (size_t)NSMAX * NROWS * 64 * 2);
  float* Lp = Mp + (size_t)NSMAX * NROWS;

  hipLaunchKernelGGL(cvt_w_kernel, dim3(12, 3), dim3(256), 0, stream,
                     Wq, Wk, Wv, Wt);
  hipLaunchKernelGGL(proj_kernel, dim3(NROWS / 64, SK), dim3(256), 0, stream,
                     x, Wt, part, CB / (64 * SK));
  hipLaunchKernelGGL(reduce_qkv_kernel, dim3(4096 + 512), dim3(256), 0, stream,
                     part, qb, kb, vT, SK);
  hipLaunchKernelGGL(attn_kernel, dim3(WGPB, NB), dim3(256), 0, stream,
                     qb, kb, vT, PO, Mp, Lp);
  hipLaunchKernelGGL(attn_reduce_kernel, dim3((NROWS * 16) / 256), dim3(256), 0, stream,
                     PO, Mp, Lp, out);
}